// Round 5
// baseline (502.183 us; speedup 1.0000x reference)
//
#include <hip/hip_runtime.h>
#include <hip/hip_bf16.h>

typedef __attribute__((ext_vector_type(8))) short short8;
typedef __attribute__((ext_vector_type(4))) float f32x4;

#define V_TAB 100001
#define B_N   4096

// ---------------------------------------------------------------------------
// Kernel 1: W fp32 -> bf16 swizzled to MFMA B-fragment streaming order.
//   dst[((((g*4+w)*8+nt)*8+ks)*64 + lane)*8 + j] = W[g][kk][n]
//   n = w*128+nt*16+(lane&15);  kk = ks*32+(lane>>4)*8+j
// ---------------------------------------------------------------------------
__global__ __launch_bounds__(256) void wprep_kernel(
    const float* __restrict__ W,          // [4][256][512]
    __hip_bfloat16* __restrict__ Wsw)     // 524288 bf16
{
    const int idx = blockIdx.x * 256 + threadIdx.x;   // == flat (g,kk,n)
    const int n   = idx & 511;
    const int kk  = (idx >> 9) & 255;
    const int g   = idx >> 17;
    const int w   = n >> 7;
    const int nt  = (n >> 4) & 7;
    const int l15 = n & 15;
    const int ks  = kk >> 5;
    const int lg  = (kk >> 3) & 3;
    const int j   = kk & 7;
    const int lane = lg * 16 + l15;
    const int dst = ((((g * 4 + w) * 8 + nt) * 8 + ks) * 64 + lane) * 8 + j;
    Wsw[dst] = __float2bfloat16(W[idx]);
}

// ---------------------------------------------------------------------------
// Kernel 2 (fused): per block = 32 rows x one group g.
//   Phase 1: gather+pool 4 features/row into LDS A-tile. Rows processed in
//            PAIRS per wave: both rows' 84 gathers are issued before either
//            is consumed (2-deep software pipeline -> no vmcnt-drain bubble).
//   Phase 2: C = A @ W[g] + b via mfma_f32_16x16x32_bf16, then LayerNorm
//            (cross-wave LDS reduce) + SiLU.
// ---------------------------------------------------------------------------
__global__ __launch_bounds__(256, 2) void fused_pool_gemm_ln(
    const int* __restrict__ feats,              // [B][168]
    const float* __restrict__ tables,           // [16][100001][64]
    const __hip_bfloat16* __restrict__ Wsw,     // swizzled bf16 W
    const float* __restrict__ bias,             // [4][512]
    const float* __restrict__ gamma,            // [4][512]
    const float* __restrict__ beta,             // [4][512]
    float* __restrict__ out)                    // [B][4][512]
{
    const int g       = blockIdx.y;
    const int rowbase = blockIdx.x * 32;
    const int wave = threadIdx.x >> 6;
    const int lane = threadIdx.x & 63;
    const int l15  = lane & 15;
    const int lg   = lane >> 4;
    const int wcol = wave * 128;

    __shared__ short lds_a[32 * 264];           // A tile: [row][k], stride 264

    // ---- Phase 1: pool 8 rows per wave, 2 rows in flight ----
    const size_t TSZ = (size_t)V_TAB * 64;
    const float* t0 = tables + (size_t)(4 * g) * TSZ;
    const float* t1 = t0 + TSZ;
    const float* t2 = t1 + TSZ;
    const float* t3 = t2 + TSZ;

    #pragma unroll 1
    for (int pr = 0; pr < 4; ++pr) {
        const int ra = wave * 8 + pr * 2;
        const int rb = ra + 1;
        const int* fra = feats + (size_t)(rowbase + ra) * 168 + g * 42;
        const int* frb = feats + (size_t)(rowbase + rb) * 168 + g * 42;

        // indices for BOTH rows
        const int a_i0 = fra[0], a_i2 = fra[21];
        const int b_i0 = frb[0], b_i2 = frb[21];
        int a_idx1[20], a_idx3[20], b_idx1[20], b_idx3[20];
        #pragma unroll
        for (int j = 0; j < 20; ++j) {
            a_idx1[j] = fra[1 + j];  a_idx3[j] = fra[22 + j];
            b_idx1[j] = frb[1 + j];  b_idx3[j] = frb[22 + j];
        }

        // issue ALL 84 gathers (independent chains) before consuming any
        const float a_v0 = t0[(size_t)a_i0 * 64 + lane];
        const float a_v2 = t2[(size_t)a_i2 * 64 + lane];
        const float b_v0 = t0[(size_t)b_i0 * 64 + lane];
        const float b_v2 = t2[(size_t)b_i2 * 64 + lane];
        float a_v1[20], a_v3[20], b_v1[20], b_v3[20];
        #pragma unroll
        for (int j = 0; j < 20; ++j) {
            a_v1[j] = t1[(size_t)a_idx1[j] * 64 + lane];
            a_v3[j] = t3[(size_t)a_idx3[j] * 64 + lane];
            b_v1[j] = t1[(size_t)b_idx1[j] * 64 + lane];
            b_v3[j] = t3[(size_t)b_idx3[j] * 64 + lane];
        }

        float aa1 = 0.f, aa3 = 0.f, ba1 = 0.f, ba3 = 0.f;
        int   ac1 = 0, ac3 = 0, bc1 = 0, bc3 = 0;
        #pragma unroll
        for (int j = 0; j < 20; ++j) {
            if (a_idx1[j] != 0) { aa1 += a_v1[j]; ++ac1; }
            if (a_idx3[j] != 0) { aa3 += a_v3[j]; ++ac3; }
            if (b_idx1[j] != 0) { ba1 += b_v1[j]; ++bc1; }
            if (b_idx3[j] != 0) { ba3 += b_v3[j]; ++bc3; }
        }
        aa1 *= 1.f / (float)(ac1 > 0 ? ac1 : 1);
        aa3 *= 1.f / (float)(ac3 > 0 ? ac3 : 1);
        ba1 *= 1.f / (float)(bc1 > 0 ? bc1 : 1);
        ba3 *= 1.f / (float)(bc3 > 0 ? bc3 : 1);

        __hip_bfloat16* rowa = (__hip_bfloat16*)(lds_a + ra * 264);
        __hip_bfloat16* rowb = (__hip_bfloat16*)(lds_a + rb * 264);
        rowa[lane]       = __float2bfloat16(a_i0 != 0 ? a_v0 : 0.f);
        rowa[64 + lane]  = __float2bfloat16(aa1);
        rowa[128 + lane] = __float2bfloat16(a_i2 != 0 ? a_v2 : 0.f);
        rowa[192 + lane] = __float2bfloat16(aa3);
        rowb[lane]       = __float2bfloat16(b_i0 != 0 ? b_v0 : 0.f);
        rowb[64 + lane]  = __float2bfloat16(ba1);
        rowb[128 + lane] = __float2bfloat16(b_i2 != 0 ? b_v2 : 0.f);
        rowb[192 + lane] = __float2bfloat16(ba3);
    }
    __syncthreads();

    // ---- Phase 2: GEMM (K=256 in 8 steps of 32) ----
    f32x4 acc[2][8];
    #pragma unroll
    for (int mt = 0; mt < 2; ++mt)
        #pragma unroll
        for (int nt = 0; nt < 8; ++nt) acc[mt][nt] = (f32x4){0.f, 0.f, 0.f, 0.f};

    const short* wptr = (const short*)Wsw + ((size_t)(g * 4 + wave) * 4096 + lane) * 8;

    short8 bcur[8], bnxt[8];
    #pragma unroll
    for (int nt = 0; nt < 8; ++nt)
        bcur[nt] = *(const short8*)(wptr + (size_t)(nt * 8) * 512);

    #pragma unroll 1
    for (int ks = 0; ks < 8; ++ks) {
        if (ks < 7) {
            #pragma unroll
            for (int nt = 0; nt < 8; ++nt)
                bnxt[nt] = *(const short8*)(wptr + (size_t)(nt * 8 + ks + 1) * 512);
        }
        const short8 a0 = *(const short8*)(lds_a + l15 * 264 + ks * 32 + lg * 8);
        const short8 a1 = *(const short8*)(lds_a + (16 + l15) * 264 + ks * 32 + lg * 8);
        #pragma unroll
        for (int nt = 0; nt < 8; ++nt) {
            acc[0][nt] = __builtin_amdgcn_mfma_f32_16x16x32_bf16(a0, bcur[nt], acc[0][nt], 0, 0, 0);
            acc[1][nt] = __builtin_amdgcn_mfma_f32_16x16x32_bf16(a1, bcur[nt], acc[1][nt], 0, 0, 0);
        }
        #pragma unroll
        for (int nt = 0; nt < 8; ++nt) bcur[nt] = bnxt[nt];
    }

    // ---- epilogue: bias, LN stats (cross-wave via LDS), SiLU, store ----
    float gv[8], tv[8];
    #pragma unroll
    for (int nt = 0; nt < 8; ++nt) {
        const int col = wcol + nt * 16 + l15;
        const float bv = bias[g * 512 + col];
        gv[nt] = gamma[g * 512 + col];
        tv[nt] = beta[g * 512 + col];
        #pragma unroll
        for (int r = 0; r < 4; ++r) { acc[0][nt][r] += bv; acc[1][nt][r] += bv; }
    }

    __shared__ float red[32][4][2];   // [row][wave][sum, sumsq]
    #pragma unroll
    for (int mt = 0; mt < 2; ++mt)
        #pragma unroll
        for (int r = 0; r < 4; ++r) {
            float s = 0.f, q = 0.f;
            #pragma unroll
            for (int nt = 0; nt < 8; ++nt) { const float v = acc[mt][nt][r]; s += v; q += v * v; }
            #pragma unroll
            for (int m = 1; m < 16; m <<= 1) { s += __shfl_xor(s, m); q += __shfl_xor(q, m); }
            if (l15 == 0) {
                const int row = mt * 16 + lg * 4 + r;
                red[row][wave][0] = s;
                red[row][wave][1] = q;
            }
        }
    __syncthreads();

    __shared__ float mu_s[32], ri_s[32];
    if (threadIdx.x < 32) {
        const int row = threadIdx.x;
        const float s = red[row][0][0] + red[row][1][0] + red[row][2][0] + red[row][3][0];
        const float q = red[row][0][1] + red[row][1][1] + red[row][2][1] + red[row][3][1];
        const float mu  = s * (1.f / 512.f);
        const float var = q * (1.f / 512.f) - mu * mu;
        mu_s[row] = mu;
        ri_s[row] = rsqrtf(var + 1e-5f);
    }
    __syncthreads();

    #pragma unroll
    for (int mt = 0; mt < 2; ++mt)
        #pragma unroll
        for (int r = 0; r < 4; ++r) {
            const int row = mt * 16 + lg * 4 + r;
            const float mu = mu_s[row];
            const float ri = ri_s[row];
            float* orow = out + ((size_t)(rowbase + row) * 4 + g) * 512 + wcol;
            #pragma unroll
            for (int nt = 0; nt < 8; ++nt) {
                const float h  = acc[mt][nt][r];
                const float hn = (h - mu) * ri * gv[nt] + tv[nt];
                orow[nt * 16 + l15] = hn / (1.f + __expf(-hn));
            }
        }
}

// ---------------------------------------------------------------------------
extern "C" void kernel_launch(void* const* d_in, const int* in_sizes, int n_in,
                              void* d_out, int out_size, void* d_ws, size_t ws_size,
                              hipStream_t stream) {
    const int*   feats  = (const int*)d_in[0];
    const float* tables = (const float*)d_in[1];
    const float* W      = (const float*)d_in[2];
    const float* bias   = (const float*)d_in[3];
    const float* gamma  = (const float*)d_in[4];
    const float* beta   = (const float*)d_in[5];
    float* out = (float*)d_out;

    __hip_bfloat16* Wsw = (__hip_bfloat16*)d_ws;   // 1 MB

    wprep_kernel<<<dim3(2048), dim3(256), 0, stream>>>(W, Wsw);
    fused_pool_gemm_ln<<<dim3(128, 4), dim3(256), 0, stream>>>(
        feats, tables, Wsw, bias, gamma, beta, out);
}